// Round 1
// baseline (297.575 us; speedup 1.0000x reference)
//
#include <hip/hip_runtime.h>
#include <hip/hip_bf16.h>
#include <stdint.h>

#define BB 1024
#define NN 8192
#define KK 4096

// Build pos[n] = k if n == info_set[k] else -1   (info_set is sorted, values unique)
__global__ void init_pos_kernel(int* __restrict__ pos) {
    int i = blockIdx.x * blockDim.x + threadIdx.x;
    if (i < NN) pos[i] = -1;
}
__global__ void scatter_pos_kernel(const int* __restrict__ info_set, int* __restrict__ pos) {
    int k = blockIdx.x * blockDim.x + threadIdx.x;
    if (k < KK) pos[info_set[k]] = k;
}

// One block per row b. 256 threads = 4 waves.
// Stage A: coalesced read of u_random row + info substitution; write f,u,p,r;
//          pack u-bits into 256 u32 words in LDS via __ballot.
// Stage B: wave 0 computes superset-XOR y[i] = XOR_{j>=i (bitwise)} u[j]
//          over the 8192 packed bits (13 commuting butterfly stages).
// Stage C: x[i] = y[bitrev13(i)]; with i = t + 256*j this is bit rev5(j) of
//          word rev8(t)  -> one LDS word per thread, coalesced float stores.
__global__ __launch_bounds__(256) void polar_main_kernel(
    const float* __restrict__ info_bits,   // (B,K) values 0.0/1.0
    const int*   __restrict__ u_random,    // (B,N) values 0/1
    const int*   __restrict__ pos,         // (N,)  k or -1
    float*       __restrict__ out)
{
    __shared__ uint32_t yw[256];

    const int b    = blockIdx.x;
    const int t    = threadIdx.x;
    const int lane = t & 63;
    const int ww   = t >> 6;

    float*  x_out = out;
    float*  f_out = out + (size_t)BB * NN;
    float*  u_out = out + 2ull * BB * NN;
    float2* p_out = (float2*)(out + 3ull * BB * NN);
    float2* r_out = (float2*)(out + 5ull * BB * NN);

    const size_t rowb  = (size_t)b * NN;
    const int*   urow  = u_random + rowb;
    const float* ibrow = info_bits + (size_t)b * KK;

    // ---- Stage A ----
    const int base = ww * 2048;
    #pragma unroll 4
    for (int it = 0; it < 32; ++it) {
        const int idx = base + it * 64 + lane;
        const int ur  = urow[idx];
        const int k   = pos[idx];
        int uval, fval;
        if (k >= 0) { uval = (int)(ibrow[k] + 0.5f); fval = 2; }
        else        { uval = ur;                     fval = ur; }

        const size_t o = rowb + idx;
        u_out[o] = (float)uval;
        f_out[o] = (float)fval;
        p_out[o] = make_float2(0.5f, 0.5f);
        r_out[o] = make_float2((float)(1 - ur), (float)ur);

        unsigned long long m = __ballot(uval);
        if (lane == 0) {
            const int w0 = idx >> 5;           // base word for these 64 bits
            yw[w0]     = (uint32_t)m;
            yw[w0 + 1] = (uint32_t)(m >> 32);
        }
    }
    __syncthreads();

    // ---- Stage B: superset-XOR butterfly on 8192 packed bits (wave 0 only) ----
    if (ww == 0) {
        uint32_t W0 = yw[lane];
        uint32_t W1 = yw[lane + 64];
        uint32_t W2 = yw[lane + 128];
        uint32_t W3 = yw[lane + 192];

        // bits 0..4 : inside each 32-bit word
        #define INWORD(W) \
            W ^= (W >> 1)  & 0x55555555u; \
            W ^= (W >> 2)  & 0x33333333u; \
            W ^= (W >> 4)  & 0x0F0F0F0Fu; \
            W ^= (W >> 8)  & 0x00FF00FFu; \
            W ^= (W >> 16) & 0x0000FFFFu;
        INWORD(W0) INWORD(W1) INWORD(W2) INWORD(W3)
        #undef INWORD

        // bits 5..10 : word-index bits 0..5 == lane bits -> shfl_xor
        #pragma unroll
        for (int wb = 0; wb < 6; ++wb) {
            const bool keep = ((lane >> wb) & 1);
            uint32_t p0 = (uint32_t)__shfl_xor((int)W0, 1 << wb);
            uint32_t p1 = (uint32_t)__shfl_xor((int)W1, 1 << wb);
            uint32_t p2 = (uint32_t)__shfl_xor((int)W2, 1 << wb);
            uint32_t p3 = (uint32_t)__shfl_xor((int)W3, 1 << wb);
            if (!keep) { W0 ^= p0; W1 ^= p1; W2 ^= p2; W3 ^= p3; }
        }

        // bits 11..12 : word-index bits 6..7 == register index k
        W0 ^= W1; W2 ^= W3;   // bit 11 (k-bit 0 == 0 updates)
        W0 ^= W2; W1 ^= W3;   // bit 12 (k-bit 1 == 0 updates)

        yw[lane]       = W0;
        yw[lane + 64]  = W1;
        yw[lane + 128] = W2;
        yw[lane + 192] = W3;
    }
    __syncthreads();

    // ---- Stage C: x[i] = y[bitrev13(i)] ----
    const uint32_t w = yw[__builtin_bitreverse32((uint32_t)t) >> 24];  // rev8(t)
    #pragma unroll
    for (int j = 0; j < 32; ++j) {
        const int sb = (int)(__builtin_bitreverse32((uint32_t)j) >> 27); // rev5(j)
        x_out[rowb + t + 256 * j] = (float)((w >> sb) & 1u);
    }
}

extern "C" void kernel_launch(void* const* d_in, const int* in_sizes, int n_in,
                              void* d_out, int out_size, void* d_ws, size_t ws_size,
                              hipStream_t stream) {
    const float* info_bits = (const float*)d_in[0];   // (B,K) float32
    const int*   u_random  = (const int*)  d_in[1];   // (B,N) int32
    const int*   info_set  = (const int*)  d_in[2];   // (K,)  int32
    float*       out       = (float*)d_out;
    int*         pos       = (int*)d_ws;              // N ints = 32 KB

    init_pos_kernel<<<NN / 256, 256, 0, stream>>>(pos);
    scatter_pos_kernel<<<KK / 256, 256, 0, stream>>>(info_set, pos);
    polar_main_kernel<<<BB, 256, 0, stream>>>(info_bits, u_random, pos, out);
}

// Round 3
// 290.046 us; speedup vs baseline: 1.0260x; 1.0260x over previous
//
#include <hip/hip_runtime.h>
#include <hip/hip_bf16.h>
#include <stdint.h>

#define BB 1024
#define NN 8192
#define KK 4096

typedef float vf4 __attribute__((ext_vector_type(4)));
typedef int   vi4 __attribute__((ext_vector_type(4)));

// pos[n] = k if n == info_set[k] else -1  (info_set sorted, unique)
__global__ void init_pos_kernel(int* __restrict__ pos) {
    int i = blockIdx.x * blockDim.x + threadIdx.x;
    if (i < NN) pos[i] = -1;
}
__global__ void scatter_pos_kernel(const int* __restrict__ info_set, int* __restrict__ pos) {
    int k = blockIdx.x * blockDim.x + threadIdx.x;
    if (k < KK) pos[info_set[k]] = k;
}

__device__ __forceinline__ void nt_store(vf4* p, vf4 v) {
    __builtin_nontemporal_store(v, p);
}
__device__ __forceinline__ vf4 mk4(float a, float b, float c, float d) {
    vf4 v; v.x = a; v.y = b; v.z = c; v.w = d; return v;
}

// One block per row. 512 threads = 8 waves.
// Stage A: int4 loads + substitution; vf4 NT stores of u,f,p,r; pack the
//          substituted bits into yw[256] via per-thread nibbles + shfl merge.
// Stage B: wave 0 computes superset-XOR over 8192 packed bits (verified R0 code).
// Stage C: x[4s..4s+3] = bit (rev11(s)&31) of words {w, w+128, w+64, w+192},
//          w = rev11(s)>>5  -> 4 LDS reads + 1 vf4 NT store.
__global__ __launch_bounds__(512, 4) void polar_main_kernel(
    const float* __restrict__ info_bits,   // (B,K) 0.0/1.0
    const int*   __restrict__ u_random,    // (B,N) 0/1
    const int*   __restrict__ pos,         // (N,)
    float*       __restrict__ out)
{
    __shared__ uint32_t yw[256];

    const int b    = blockIdx.x;
    const int t    = threadIdx.x;
    const int lane = t & 63;
    const int ww   = t >> 6;

    vf4* x4 = (vf4*)(out)                 + (size_t)b * (NN / 4);
    vf4* f4 = (vf4*)(out + (size_t)BB*NN) + (size_t)b * (NN / 4);
    vf4* u4 = (vf4*)(out + 2ull*BB*NN)    + (size_t)b * (NN / 4);
    vf4* p4 = (vf4*)(out + 3ull*BB*NN)    + (size_t)b * (NN / 2);
    vf4* r4 = (vf4*)(out + 5ull*BB*NN)    + (size_t)b * (NN / 2);

    const vi4*   ur4p  = (const vi4*)(u_random + (size_t)b * NN);
    const vi4*   pos4p = (const vi4*)pos;
    const float* ibrow = info_bits + (size_t)b * KK;

    // ---- Stage A ----
    #pragma unroll
    for (int it = 0; it < 4; ++it) {
        const int idx4 = it * 512 + t;           // coalesced across lanes
        const vi4 ur = ur4p[idx4];
        const vi4 kk = pos4p[idx4];

        int u0 = ur.x, u1 = ur.y, u2 = ur.z, u3 = ur.w;
        int f0 = u0,   f1 = u1,   f2 = u2,   f3 = u3;
        if (kk.x >= 0) { u0 = ibrow[kk.x] > 0.5f; f0 = 2; }
        if (kk.y >= 0) { u1 = ibrow[kk.y] > 0.5f; f1 = 2; }
        if (kk.z >= 0) { u2 = ibrow[kk.z] > 0.5f; f2 = 2; }
        if (kk.w >= 0) { u3 = ibrow[kk.w] > 0.5f; f3 = 2; }

        nt_store(&u4[idx4], mk4((float)u0, (float)u1, (float)u2, (float)u3));
        nt_store(&f4[idx4], mk4((float)f0, (float)f1, (float)f2, (float)f3));
        nt_store(&p4[idx4 * 2],     mk4(0.5f, 0.5f, 0.5f, 0.5f));
        nt_store(&p4[idx4 * 2 + 1], mk4(0.5f, 0.5f, 0.5f, 0.5f));
        nt_store(&r4[idx4 * 2],
                 mk4((float)(1 - ur.x), (float)ur.x, (float)(1 - ur.y), (float)ur.y));
        nt_store(&r4[idx4 * 2 + 1],
                 mk4((float)(1 - ur.z), (float)ur.z, (float)(1 - ur.w), (float)ur.w));

        // pack 4 substituted bits -> nibble; merge 8 lanes -> one u32 word
        uint32_t x = (uint32_t)(u0 | (u1 << 1) | (u2 << 2) | (u3 << 3));
        x |= ((uint32_t)__shfl_xor((int)x, 1)) << 4;   // lanes with (l&1)==0 valid
        x |= ((uint32_t)__shfl_xor((int)x, 2)) << 8;   // (l&3)==0 valid
        x |= ((uint32_t)__shfl_xor((int)x, 4)) << 16;  // (l&7)==0 valid
        if ((lane & 7) == 0)
            yw[it * 64 + ww * 8 + (lane >> 3)] = x;    // word = idx4>>3
    }
    __syncthreads();

    // ---- Stage B: superset-XOR butterfly on 8192 packed bits (wave 0) ----
    if (ww == 0) {
        uint32_t W0 = yw[lane];
        uint32_t W1 = yw[lane + 64];
        uint32_t W2 = yw[lane + 128];
        uint32_t W3 = yw[lane + 192];

        #define INWORD(W) \
            W ^= (W >> 1)  & 0x55555555u; \
            W ^= (W >> 2)  & 0x33333333u; \
            W ^= (W >> 4)  & 0x0F0F0F0Fu; \
            W ^= (W >> 8)  & 0x00FF00FFu; \
            W ^= (W >> 16) & 0x0000FFFFu;
        INWORD(W0) INWORD(W1) INWORD(W2) INWORD(W3)
        #undef INWORD

        #pragma unroll
        for (int wb = 0; wb < 6; ++wb) {
            const bool keep = ((lane >> wb) & 1);
            uint32_t p0 = (uint32_t)__shfl_xor((int)W0, 1 << wb);
            uint32_t p1 = (uint32_t)__shfl_xor((int)W1, 1 << wb);
            uint32_t p2 = (uint32_t)__shfl_xor((int)W2, 1 << wb);
            uint32_t p3 = (uint32_t)__shfl_xor((int)W3, 1 << wb);
            if (!keep) { W0 ^= p0; W1 ^= p1; W2 ^= p2; W3 ^= p3; }
        }

        W0 ^= W1; W2 ^= W3;   // word-index bit 6
        W0 ^= W2; W1 ^= W3;   // word-index bit 7

        yw[lane]       = W0;
        yw[lane + 64]  = W1;
        yw[lane + 128] = W2;
        yw[lane + 192] = W3;
    }
    __syncthreads();

    // ---- Stage C: x[i] = y[rev13(i)], emitted as vf4 ----
    #pragma unroll
    for (int it = 0; it < 4; ++it) {
        const int s = it * 512 + t;
        const uint32_t q = __builtin_bitreverse32((uint32_t)s) >> 21;  // rev11(s)
        const int w   = (int)(q >> 5);       // distinct per lane -> 2-way bank alias, free
        const int bsh = (int)(q & 31u);      // wave-uniform
        const float x0 = (float)((yw[w]       >> bsh) & 1u);
        const float x1 = (float)((yw[w + 128] >> bsh) & 1u);
        const float x2 = (float)((yw[w + 64]  >> bsh) & 1u);
        const float x3 = (float)((yw[w + 192] >> bsh) & 1u);
        nt_store(&x4[s], mk4(x0, x1, x2, x3));
    }
}

extern "C" void kernel_launch(void* const* d_in, const int* in_sizes, int n_in,
                              void* d_out, int out_size, void* d_ws, size_t ws_size,
                              hipStream_t stream) {
    const float* info_bits = (const float*)d_in[0];   // (B,K) float32
    const int*   u_random  = (const int*)  d_in[1];   // (B,N) int32
    const int*   info_set  = (const int*)  d_in[2];   // (K,)  int32
    float*       out       = (float*)d_out;
    int*         pos       = (int*)d_ws;              // N ints = 32 KB

    init_pos_kernel<<<NN / 256, 256, 0, stream>>>(pos);
    scatter_pos_kernel<<<KK / 256, 256, 0, stream>>>(info_set, pos);
    polar_main_kernel<<<BB, 512, 0, stream>>>(info_bits, u_random, pos, out);
}

// Round 5
// 275.273 us; speedup vs baseline: 1.0810x; 1.0537x over previous
//
#include <hip/hip_runtime.h>
#include <hip/hip_bf16.h>
#include <stdint.h>

#define BB 1024
#define NN 8192
#define KK 4096

typedef float vf4 __attribute__((ext_vector_type(4)));
typedef int   vi4 __attribute__((ext_vector_type(4)));
typedef int   vi2 __attribute__((ext_vector_type(2)));

// pos[n] = k if n == info_set[k] else -1  (info_set sorted, unique)
__global__ void init_pos_kernel(int* __restrict__ pos) {
    int i = blockIdx.x * blockDim.x + threadIdx.x;
    if (i < NN) pos[i] = -1;
}
__global__ void scatter_pos_kernel(const int* __restrict__ info_set, int* __restrict__ pos) {
    int k = blockIdx.x * blockDim.x + threadIdx.x;
    if (k < KK) pos[info_set[k]] = k;
}

__device__ __forceinline__ void nt_store(vf4* p, vf4 v) {
    __builtin_nontemporal_store(v, p);
}
__device__ __forceinline__ vf4 mk4(float a, float b, float c, float d) {
    vf4 v; v.x = a; v.y = b; v.z = c; v.w = d; return v;
}

// One block per row. 512 threads = 8 waves. ALL store instructions are
// lane-contiguous (lane i writes base + 16B*i) — no gapped NT bursts.
// Per-row vf4 region sizes: x/f/u = NN/4 = 2048; p/r = NN*2/4 = 4096.
__global__ __launch_bounds__(512) void polar_main_kernel(
    const float* __restrict__ info_bits,   // (B,K) 0.0/1.0
    const int*   __restrict__ u_random,    // (B,N) 0/1
    const int*   __restrict__ pos,         // (N,)
    float*       __restrict__ out)
{
    __shared__ uint32_t yw[256];

    const int b    = blockIdx.x;
    const int t    = threadIdx.x;
    const int lane = t & 63;
    const int ww   = t >> 6;

    vf4* x4 = (vf4*)(out)                 + (size_t)b * (NN / 4);
    vf4* f4 = (vf4*)(out + (size_t)BB*NN) + (size_t)b * (NN / 4);
    vf4* u4 = (vf4*)(out + 2ull*BB*NN)    + (size_t)b * (NN / 4);
    vf4* p4 = (vf4*)(out + 3ull*BB*NN)    + (size_t)b * (NN / 2);
    vf4* r4 = (vf4*)(out + 5ull*BB*NN)    + (size_t)b * (NN / 2);

    const vi4*   ur4p  = (const vi4*)(u_random + (size_t)b * NN);
    const vi2*   ur2p  = (const vi2*)(u_random + (size_t)b * NN);
    const vi4*   pos4p = (const vi4*)pos;
    const float* ibrow = info_bits + (size_t)b * KK;

    // ---- Stage A: u, f, bit-pack ----
    #pragma unroll
    for (int it = 0; it < 4; ++it) {
        const int idx4 = it * 512 + t;           // coalesced across lanes
        const vi4 ur = ur4p[idx4];
        const vi4 kk = pos4p[idx4];

        int u0 = ur.x, u1 = ur.y, u2 = ur.z, u3 = ur.w;
        int f0 = u0,   f1 = u1,   f2 = u2,   f3 = u3;
        if (kk.x >= 0) { u0 = ibrow[kk.x] > 0.5f; f0 = 2; }
        if (kk.y >= 0) { u1 = ibrow[kk.y] > 0.5f; f1 = 2; }
        if (kk.z >= 0) { u2 = ibrow[kk.z] > 0.5f; f2 = 2; }
        if (kk.w >= 0) { u3 = ibrow[kk.w] > 0.5f; f3 = 2; }

        nt_store(&u4[idx4], mk4((float)u0, (float)u1, (float)u2, (float)u3));
        nt_store(&f4[idx4], mk4((float)f0, (float)f1, (float)f2, (float)f3));

        // pack 4 substituted bits -> nibble; merge 8 lanes -> one u32 word
        uint32_t x = (uint32_t)(u0 | (u1 << 1) | (u2 << 2) | (u3 << 3));
        x |= ((uint32_t)__shfl_xor((int)x, 1)) << 4;
        x |= ((uint32_t)__shfl_xor((int)x, 2)) << 8;
        x |= ((uint32_t)__shfl_xor((int)x, 4)) << 16;
        if ((lane & 7) == 0)
            yw[it * 64 + ww * 8 + (lane >> 3)] = x;    // word = idx4>>3
    }

    // ---- Stage R: r (vi2 reload is L2-hot; every store lane-contiguous) ----
    #pragma unroll
    for (int c = 0; c < 8; ++c) {
        const int j = c * 512 + t;               // vf4 index, 4096 total
        const vi2 ur = ur2p[j];
        nt_store(&r4[j], mk4((float)(1 - ur.x), (float)ur.x,
                             (float)(1 - ur.y), (float)ur.y));
    }

    // ---- Stage P: constant 0.5 (4096 vf4 per row) ----
    const vf4 half = mk4(0.5f, 0.5f, 0.5f, 0.5f);
    #pragma unroll
    for (int c = 0; c < 8; ++c)
        nt_store(&p4[c * 512 + t], half);

    __syncthreads();

    // ---- Stage B: superset-XOR butterfly on 8192 packed bits (wave 0) ----
    if (ww == 0) {
        uint32_t W0 = yw[lane];
        uint32_t W1 = yw[lane + 64];
        uint32_t W2 = yw[lane + 128];
        uint32_t W3 = yw[lane + 192];

        #define INWORD(W) \
            W ^= (W >> 1)  & 0x55555555u; \
            W ^= (W >> 2)  & 0x33333333u; \
            W ^= (W >> 4)  & 0x0F0F0F0Fu; \
            W ^= (W >> 8)  & 0x00FF00FFu; \
            W ^= (W >> 16) & 0x0000FFFFu;
        INWORD(W0) INWORD(W1) INWORD(W2) INWORD(W3)
        #undef INWORD

        #pragma unroll
        for (int wb = 0; wb < 6; ++wb) {
            const bool keep = ((lane >> wb) & 1);
            uint32_t p0 = (uint32_t)__shfl_xor((int)W0, 1 << wb);
            uint32_t p1 = (uint32_t)__shfl_xor((int)W1, 1 << wb);
            uint32_t p2 = (uint32_t)__shfl_xor((int)W2, 1 << wb);
            uint32_t p3 = (uint32_t)__shfl_xor((int)W3, 1 << wb);
            if (!keep) { W0 ^= p0; W1 ^= p1; W2 ^= p2; W3 ^= p3; }
        }

        W0 ^= W1; W2 ^= W3;   // word-index bit 6
        W0 ^= W2; W1 ^= W3;   // word-index bit 7

        yw[lane]       = W0;
        yw[lane + 64]  = W1;
        yw[lane + 128] = W2;
        yw[lane + 192] = W3;
    }
    __syncthreads();

    // ---- Stage C: x[i] = y[rev13(i)], emitted as vf4 ----
    #pragma unroll
    for (int it = 0; it < 4; ++it) {
        const int s = it * 512 + t;
        const uint32_t q = __builtin_bitreverse32((uint32_t)s) >> 21;  // rev11(s)
        const int w   = (int)(q >> 5);       // distinct per lane -> 2-way bank alias, free
        const int bsh = (int)(q & 31u);      // wave-uniform
        const float x0 = (float)((yw[w]       >> bsh) & 1u);
        const float x1 = (float)((yw[w + 128] >> bsh) & 1u);
        const float x2 = (float)((yw[w + 64]  >> bsh) & 1u);
        const float x3 = (float)((yw[w + 192] >> bsh) & 1u);
        nt_store(&x4[s], mk4(x0, x1, x2, x3));
    }
}

extern "C" void kernel_launch(void* const* d_in, const int* in_sizes, int n_in,
                              void* d_out, int out_size, void* d_ws, size_t ws_size,
                              hipStream_t stream) {
    const float* info_bits = (const float*)d_in[0];   // (B,K) float32
    const int*   u_random  = (const int*)  d_in[1];   // (B,N) int32
    const int*   info_set  = (const int*)  d_in[2];   // (K,)  int32
    float*       out       = (float*)d_out;
    int*         pos       = (int*)d_ws;              // N ints = 32 KB

    init_pos_kernel<<<NN / 256, 256, 0, stream>>>(pos);
    scatter_pos_kernel<<<KK / 256, 256, 0, stream>>>(info_set, pos);
    polar_main_kernel<<<BB, 512, 0, stream>>>(info_bits, u_random, pos, out);
}

// Round 6
// 272.127 us; speedup vs baseline: 1.0935x; 1.0116x over previous
//
#include <hip/hip_runtime.h>
#include <hip/hip_bf16.h>
#include <stdint.h>

#define BB 1024
#define NN 8192
#define KK 4096

typedef float vf4 __attribute__((ext_vector_type(4)));
typedef int   vi4 __attribute__((ext_vector_type(4)));
typedef int   vi2 __attribute__((ext_vector_type(2)));

// pos[n] = k if n == info_set[k] else -1  (info_set sorted, unique)
__global__ void init_pos_kernel(int* __restrict__ pos) {
    int i = blockIdx.x * blockDim.x + threadIdx.x;
    if (i < NN) pos[i] = -1;
}
__global__ void scatter_pos_kernel(const int* __restrict__ info_set, int* __restrict__ pos) {
    int k = blockIdx.x * blockDim.x + threadIdx.x;
    if (k < KK) pos[info_set[k]] = k;
}

__device__ __forceinline__ vf4 mk4(float a, float b, float c, float d) {
    vf4 v; v.x = a; v.y = b; v.z = c; v.w = d; return v;
}

// One block per row. 512 threads = 8 waves. All store instructions are
// lane-contiguous PLAIN stores (fills prove plain stores sustain 6.4 TB/s;
// NT was the untested variable). Only u/f stores precede the barrier, so the
// implicit vmcnt(0)-before-s_barrier drains 128B/thread, not 448B.
__global__ __launch_bounds__(512) void polar_main_kernel(
    const float* __restrict__ info_bits,   // (B,K) 0.0/1.0
    const int*   __restrict__ u_random,    // (B,N) 0/1
    const int*   __restrict__ pos,         // (N,)
    float*       __restrict__ out)
{
    __shared__ uint32_t yw[256];

    const int b    = blockIdx.x;
    const int t    = threadIdx.x;
    const int lane = t & 63;
    const int ww   = t >> 6;

    vf4* x4 = (vf4*)(out)                 + (size_t)b * (NN / 4);
    vf4* f4 = (vf4*)(out + (size_t)BB*NN) + (size_t)b * (NN / 4);
    vf4* u4 = (vf4*)(out + 2ull*BB*NN)    + (size_t)b * (NN / 4);
    vf4* p4 = (vf4*)(out + 3ull*BB*NN)    + (size_t)b * (NN / 2);
    vf4* r4 = (vf4*)(out + 5ull*BB*NN)    + (size_t)b * (NN / 2);

    const vi4*   ur4p  = (const vi4*)(u_random + (size_t)b * NN);
    const vi2*   ur2p  = (const vi2*)(u_random + (size_t)b * NN);
    const vi4*   pos4p = (const vi4*)pos;
    const float* ibrow = info_bits + (size_t)b * KK;

    // ---- Stage A: u, f, bit-pack ----
    #pragma unroll
    for (int it = 0; it < 4; ++it) {
        const int idx4 = it * 512 + t;           // coalesced across lanes
        const vi4 ur = ur4p[idx4];
        const vi4 kk = pos4p[idx4];

        int u0 = ur.x, u1 = ur.y, u2 = ur.z, u3 = ur.w;
        int f0 = u0,   f1 = u1,   f2 = u2,   f3 = u3;
        if (kk.x >= 0) { u0 = ibrow[kk.x] > 0.5f; f0 = 2; }
        if (kk.y >= 0) { u1 = ibrow[kk.y] > 0.5f; f1 = 2; }
        if (kk.z >= 0) { u2 = ibrow[kk.z] > 0.5f; f2 = 2; }
        if (kk.w >= 0) { u3 = ibrow[kk.w] > 0.5f; f3 = 2; }

        u4[idx4] = mk4((float)u0, (float)u1, (float)u2, (float)u3);
        f4[idx4] = mk4((float)f0, (float)f1, (float)f2, (float)f3);

        // pack 4 substituted bits -> nibble; merge 8 lanes -> one u32 word
        uint32_t x = (uint32_t)(u0 | (u1 << 1) | (u2 << 2) | (u3 << 3));
        x |= ((uint32_t)__shfl_xor((int)x, 1)) << 4;
        x |= ((uint32_t)__shfl_xor((int)x, 2)) << 8;
        x |= ((uint32_t)__shfl_xor((int)x, 4)) << 16;
        if ((lane & 7) == 0)
            yw[it * 64 + ww * 8 + (lane >> 3)] = x;    // word = idx4>>3
    }
    __syncthreads();

    // ---- Stage B: superset-XOR butterfly on 8192 packed bits (wave 0) ----
    if (ww == 0) {
        uint32_t W0 = yw[lane];
        uint32_t W1 = yw[lane + 64];
        uint32_t W2 = yw[lane + 128];
        uint32_t W3 = yw[lane + 192];

        #define INWORD(W) \
            W ^= (W >> 1)  & 0x55555555u; \
            W ^= (W >> 2)  & 0x33333333u; \
            W ^= (W >> 4)  & 0x0F0F0F0Fu; \
            W ^= (W >> 8)  & 0x00FF00FFu; \
            W ^= (W >> 16) & 0x0000FFFFu;
        INWORD(W0) INWORD(W1) INWORD(W2) INWORD(W3)
        #undef INWORD

        #pragma unroll
        for (int wb = 0; wb < 6; ++wb) {
            const bool keep = ((lane >> wb) & 1);
            uint32_t p0 = (uint32_t)__shfl_xor((int)W0, 1 << wb);
            uint32_t p1 = (uint32_t)__shfl_xor((int)W1, 1 << wb);
            uint32_t p2 = (uint32_t)__shfl_xor((int)W2, 1 << wb);
            uint32_t p3 = (uint32_t)__shfl_xor((int)W3, 1 << wb);
            if (!keep) { W0 ^= p0; W1 ^= p1; W2 ^= p2; W3 ^= p3; }
        }

        W0 ^= W1; W2 ^= W3;   // word-index bit 6
        W0 ^= W2; W1 ^= W3;   // word-index bit 7

        yw[lane]       = W0;
        yw[lane + 64]  = W1;
        yw[lane + 128] = W2;
        yw[lane + 192] = W3;
    }
    __syncthreads();

    // ---- Stage C: x[i] = y[rev13(i)], emitted as vf4 ----
    #pragma unroll
    for (int it = 0; it < 4; ++it) {
        const int s = it * 512 + t;
        const uint32_t q = __builtin_bitreverse32((uint32_t)s) >> 21;  // rev11(s)
        const int w   = (int)(q >> 5);       // distinct per lane -> 2-way bank alias, free
        const int bsh = (int)(q & 31u);      // wave-uniform
        const float x0 = (float)((yw[w]       >> bsh) & 1u);
        const float x1 = (float)((yw[w + 128] >> bsh) & 1u);
        const float x2 = (float)((yw[w + 64]  >> bsh) & 1u);
        const float x3 = (float)((yw[w + 192] >> bsh) & 1u);
        x4[s] = mk4(x0, x1, x2, x3);
    }

    // ---- Stage R: r (vi2 reload is L2-hot; lane-contiguous stores) ----
    #pragma unroll
    for (int c = 0; c < 8; ++c) {
        const int j = c * 512 + t;               // vf4 index, 4096 total
        const vi2 ur = ur2p[j];
        r4[j] = mk4((float)(1 - ur.x), (float)ur.x,
                    (float)(1 - ur.y), (float)ur.y);
    }

    // ---- Stage P: constant 0.5 (4096 vf4 per row) ----
    const vf4 half = mk4(0.5f, 0.5f, 0.5f, 0.5f);
    #pragma unroll
    for (int c = 0; c < 8; ++c)
        p4[c * 512 + t] = half;
}

extern "C" void kernel_launch(void* const* d_in, const int* in_sizes, int n_in,
                              void* d_out, int out_size, void* d_ws, size_t ws_size,
                              hipStream_t stream) {
    const float* info_bits = (const float*)d_in[0];   // (B,K) float32
    const int*   u_random  = (const int*)  d_in[1];   // (B,N) int32
    const int*   info_set  = (const int*)  d_in[2];   // (K,)  int32
    float*       out       = (float*)d_out;
    int*         pos       = (int*)d_ws;              // N ints = 32 KB

    init_pos_kernel<<<NN / 256, 256, 0, stream>>>(pos);
    scatter_pos_kernel<<<KK / 256, 256, 0, stream>>>(info_set, pos);
    polar_main_kernel<<<BB, 512, 0, stream>>>(info_bits, u_random, pos, out);
}